// Round 9
// baseline (613.901 us; speedup 1.0000x reference)
//
#include <hip/hip_runtime.h>

// LSTM-GCN single step from (H=0, C=0).
// R9 = R8 with the host-side __device__-symbol bug fixed: scan kernels now
// select their target buffer (g_h / g_h2) INSIDE device code via a flag.
// (R8 passed &g_h from host -> host shadow address -> fault.)
//
// Design: MSD 2-pass counting sort (<=128 bins/pass -> coalesced scatter runs),
// key = dstbin(32 nodes)*4 + src-quarter (2MB bf16 xs window per quarter for
// L2 locality in gather). Deg via fused 196-bin src sort + LDS segmented sum.
// No global atomics anywhere.

#define FDIM 32
#define MAX_N 100000
#define MAX_E 1600000
#define T1 4096              // sort tile / pass-2 chunk
#define NBLK_MAX 400
#define NC_MAX 98            // coarse dst bins (dst>>10)
#define NS_MAX 196           // src bins for deg (src>>9)
#define NF 128               // fine bins: ((dst>>5)&31)<<2 | (src>>15)
#define NCH 12               // max chunks per coarse segment (covers <=49k recs)

__device__ float          g_dinv[MAX_N];
__device__ unsigned short g_xs[MAX_N * FDIM];   // bf16 of dinv*x
__device__ int   g_h[(NC_MAX + NS_MAX) * NBLK_MAX];
__device__ int   g_h2[NC_MAX * NF * NCH];
__device__ int   g_blk[1024];
__device__ int   g_tot[2];
__device__ unsigned       g_A1[MAX_E];          // src | dl<<17
__device__ unsigned short g_K1[MAX_E];          // fine key
__device__ float          g_W1[MAX_E];
__device__ unsigned       g_A2[MAX_E];
__device__ float          g_W2[MAX_E];
__device__ uint2          g_D[MAX_E];           // {src&511, w bits}
__device__ float g_tx1[MAX_N * FDIM];

// ---- pass1 histograms: 98 coarse dst bins + 196 src bins, one ei read ------
__global__ __launch_bounds__(256) void count1_kernel(const int* __restrict__ ei,
                                                     int E, int n, int nblk,
                                                     int nc, int ns) {
    __shared__ int h[NC_MAX + NS_MAX];
    int tot = nc + ns;
    for (int i = threadIdx.x; i < tot; i += 256) h[i] = 0;
    __syncthreads();
    int base = blockIdx.x * T1, lim = min(T1, E - base);
    for (int t = threadIdx.x; t < lim; t += 256) {
        int e = base + t;
        int s = ei[e], d = ei[E + e];
        if ((unsigned)s >= (unsigned)n || (unsigned)d >= (unsigned)n) continue;
        atomicAdd(&h[d >> 10], 1);
        atomicAdd(&h[nc + (s >> 9)], 1);
    }
    __syncthreads();
    for (int i = threadIdx.x; i < tot; i += 256)
        g_h[i * nblk + blockIdx.x] = h[i];
}

// ---- generic 3-kernel exclusive scan (buffer chosen in device code!) -------
__global__ __launch_bounds__(1024) void scan1_kernel(int which, int n) {
    int* buf = which ? g_h2 : g_h;
    __shared__ int sh[1024];
    int tid = threadIdx.x;
    int base = blockIdx.x * 8192 + tid * 8;
    int v[8];
#pragma unroll
    for (int i = 0; i < 8; ++i) v[i] = (base + i < n) ? buf[base + i] : 0;
    int tsum = 0;
#pragma unroll
    for (int i = 0; i < 8; ++i) tsum += v[i];
    sh[tid] = tsum;
    __syncthreads();
    for (int off = 1; off < 1024; off <<= 1) {
        int t = (tid >= off) ? sh[tid - off] : 0;
        __syncthreads();
        sh[tid] += t;
        __syncthreads();
    }
    if (tid == 1023) g_blk[blockIdx.x] = sh[1023];
    int run = sh[tid] - tsum;
#pragma unroll
    for (int i = 0; i < 8; ++i) {
        if (base + i < n) buf[base + i] = run;
        run += v[i];
    }
}

__global__ __launch_bounds__(256) void scan2_kernel(int which, int nb) {
    __shared__ int sh[256];
    int tid = threadIdx.x;
    int base = tid * 4;
    int v[4];
#pragma unroll
    for (int i = 0; i < 4; ++i) v[i] = (base + i < nb) ? g_blk[base + i] : 0;
    int tsum = v[0] + v[1] + v[2] + v[3];
    sh[tid] = tsum;
    __syncthreads();
    for (int off = 1; off < 256; off <<= 1) {
        int t = (tid >= off) ? sh[tid - off] : 0;
        __syncthreads();
        sh[tid] += t;
        __syncthreads();
    }
    if (tid == 255) g_tot[which] = sh[255];
    int run = sh[tid] - tsum;
#pragma unroll
    for (int i = 0; i < 4; ++i) {
        if (base + i < nb) g_blk[base + i] = run;
        run += v[i];
    }
}

__global__ __launch_bounds__(1024) void scan3_kernel(int which, int n) {
    int* buf = which ? g_h2 : g_h;
    int off = g_blk[blockIdx.x];
    int base = blockIdx.x * 8192 + threadIdx.x * 8;
#pragma unroll
    for (int i = 0; i < 8; ++i)
        if (base + i < n) buf[base + i] += off;
}

// ---- pass1 scatter (coarse dst sort + src sort), LDS cursors ---------------
__global__ __launch_bounds__(256) void scatter1_kernel(const int* __restrict__ ei,
                                                       const float* __restrict__ w,
                                                       int E, int n, int nblk,
                                                       int nc, int ns) {
    __shared__ int cur[NC_MAX + NS_MAX];
    int tot = nc + ns;
    int EV = g_h[nc * nblk];                  // total valid edges
    for (int i = threadIdx.x; i < tot; i += 256) {
        int v = g_h[i * nblk + blockIdx.x];
        cur[i] = (i >= nc) ? v - EV : v;
    }
    __syncthreads();
    int base = blockIdx.x * T1, lim = min(T1, E - base);
    for (int t = threadIdx.x; t < lim; t += 256) {
        int e = base + t;
        int s = ei[e], d = ei[E + e];
        if ((unsigned)s >= (unsigned)n || (unsigned)d >= (unsigned)n) continue;
        float we = (s == d) ? 0.f : w[e];
        int pA = atomicAdd(&cur[d >> 10], 1);                 // LDS atomic
        g_A1[pA] = (unsigned)s | ((unsigned)(d & 31) << 17);
        g_K1[pA] = (unsigned short)((((d >> 5) & 31) << 2) | (s >> 15));
        g_W1[pA] = we;
        int pD = atomicAdd(&cur[nc + (s >> 9)], 1);           // LDS atomic
        g_D[pD] = make_uint2((unsigned)(s & 511), __float_as_uint(we));
    }
}

// ---- pass2: per-coarse-segment counting sort into 128 fine bins ------------
__global__ __launch_bounds__(256) void count2_kernel(int nblk) {
    int c = blockIdx.x / NCH, ch = blockIdx.x % NCH;
    int s0 = g_h[c * nblk], s1 = g_h[(c + 1) * nblk];
    int w0 = s0 + ch * T1, w1 = min(w0 + T1, s1);
    __shared__ int h[NF];
    if (threadIdx.x < NF) h[threadIdx.x] = 0;
    __syncthreads();
    for (int i = w0 + threadIdx.x; i < w1; i += 256)
        atomicAdd(&h[g_K1[i]], 1);
    __syncthreads();
    if (threadIdx.x < NF)
        g_h2[(c * NF + threadIdx.x) * NCH + ch] = h[threadIdx.x];
}

__global__ __launch_bounds__(256) void scatter2_kernel(int nblk) {
    int c = blockIdx.x / NCH, ch = blockIdx.x % NCH;
    int s0 = g_h[c * nblk], s1 = g_h[(c + 1) * nblk];
    int w0 = s0 + ch * T1, w1 = min(w0 + T1, s1);
    __shared__ int cur[NF];
    if (threadIdx.x < NF)
        cur[threadIdx.x] = g_h2[(c * NF + threadIdx.x) * NCH + ch];
    __syncthreads();
    for (int i = w0 + threadIdx.x; i < w1; i += 256) {
        int f = g_K1[i];
        int p = atomicAdd(&cur[f], 1);        // LDS atomic
        g_A2[p] = g_A1[i];
        g_W2[p] = g_W1[i];
    }
}

// ---- deg (512-node bins, LDS segmented sum) + fused bf16 xs prescale -------
__global__ __launch_bounds__(256) void degk_kernel(const float* __restrict__ x,
                                                   int n, int nblk, int nc, int ns) {
    __shared__ float dg[512];
    __shared__ float dv[512];
    int b = blockIdx.x, tid = threadIdx.x;
    for (int i = tid; i < 512; i += 256) dg[i] = 0.f;
    __syncthreads();
    int EV = g_h[nc * nblk];
    int start = g_h[(nc + b) * nblk] - EV;
    int end = (b + 1 < ns) ? g_h[(nc + b + 1) * nblk] - EV : g_tot[0] - EV;
    for (int i = start + tid; i < end; i += 256) {
        uint2 r = g_D[i];
        atomicAdd(&dg[r.x], __uint_as_float(r.y));            // LDS atomic
    }
    __syncthreads();
    for (int i = tid; i < 512; i += 256) {
        float g = dg[i];
        float v = (g > 0.f) ? rsqrtf(g) : 0.f;
        dv[i] = v;
        int node = b * 512 + i;
        if (node < n) g_dinv[node] = v;
    }
    __syncthreads();
    int nb0 = b * 512;
    for (int j = tid; j < 512 * FDIM; j += 256) {
        int node = nb0 + (j >> 5);
        if (node < n) {
            float vv = x[node * FDIM + (j & 31)] * dv[j >> 5];
            unsigned bb = __float_as_uint(vv);
            unsigned rb = (bb + 0x7FFFu + ((bb >> 16) & 1u)) >> 16;   // RNE
            g_xs[node * FDIM + (j & 31)] = (unsigned short)rb;
        }
    }
}

// ---- gather: one block per 32-node dst bin; records srcq-grouped -----------
__global__ __launch_bounds__(256) void gather_kernel(int n, int nblk, int nc) {
    __shared__ float acc[32 * FDIM];
    __shared__ float dneg[32];
    int tid = threadIdx.x, bin = blockIdx.x;
    for (int i = tid; i < 32 * FDIM; i += 256) acc[i] = 0.f;
    if (tid < 32) {
        int node = bin * 32 + tid;
        dneg[tid] = (node < n) ? -g_dinv[node] : 0.f;
    }
    __syncthreads();
    int c = bin >> 5, f0 = (bin & 31) << 2;
    int i0 = g_h2[(c * NF + f0) * NCH];
    int eidx = (c * NF + f0 + 4) * NCH;
    int i1 = (eidx < nc * NF * NCH) ? g_h2[eidx] : g_h[nc * nblk];
    int hw = tid >> 5, f = tid & 31;
    int i = i0 + hw;
    for (; i + 56 < i1; i += 64) {           // 8 half-waves x unroll-8
        unsigned a[8];
        float wv[8], xv[8];
#pragma unroll
        for (int j = 0; j < 8; ++j) a[j] = g_A2[i + 8 * j];
#pragma unroll
        for (int j = 0; j < 8; ++j) wv[j] = g_W2[i + 8 * j];
#pragma unroll
        for (int j = 0; j < 8; ++j) {
            unsigned short u = g_xs[(a[j] & 0x1FFFF) * FDIM + f];
            xv[j] = __uint_as_float(((unsigned)u) << 16);
        }
#pragma unroll
        for (int j = 0; j < 8; ++j) {
            int dl = (a[j] >> 17) & 31;
            atomicAdd(&acc[dl * FDIM + f], dneg[dl] * wv[j] * xv[j]);  // LDS
        }
    }
    for (; i < i1; i += 8) {
        unsigned a = g_A2[i];
        int dl = (a >> 17) & 31;
        unsigned short u = g_xs[(a & 0x1FFFF) * FDIM + f];
        atomicAdd(&acc[dl * FDIM + f],
                  dneg[dl] * g_W2[i] * __uint_as_float(((unsigned)u) << 16));
    }
    __syncthreads();
    int nodeb = bin * 32;
    for (int j = tid; j < 32 * FDIM; j += 256) {
        int node = nodeb + (j >> 5);
        if (node < n) g_tx1[node * FDIM + (j & 31)] = acc[j];
    }
}

// ---- gates + epilogue (unchanged; correctness-proven) ----------------------
__global__ __launch_bounds__(256) void gates_kernel(
    const float* __restrict__ x,
    const float* __restrict__ Wx, const float* __restrict__ bx,
    const float* __restrict__ bh, const float* __restrict__ wc,
    const float* __restrict__ bg, const float* __restrict__ lin_w,
    const float* __restrict__ lin_b, float* __restrict__ out, int n_nodes) {
    __shared__ float Ws[3 * 2048];
    __shared__ float xs[8 * FDIM];
    __shared__ float ts[8 * FDIM];
    for (int idx = threadIdx.x; idx < 2048; idx += 256) {
        Ws[idx]        = Wx[0 * 2048 + idx];
        Ws[2048 + idx] = Wx[2 * 2048 + idx];
        Ws[4096 + idx] = Wx[3 * 2048 + idx];
    }
    int node0 = blockIdx.x * 8;
    {
        int n = node0 + (threadIdx.x >> 5);
        int f = threadIdx.x & 31;
        if (n < n_nodes) {
            xs[threadIdx.x] = x[n * FDIM + f];
            ts[threadIdx.x] = g_tx1[n * FDIM + f];
        }
    }
    __syncthreads();
    int ln = threadIdx.x >> 5;
    int j  = threadIdx.x & 31;
    int n  = node0 + ln;
    if (n >= n_nodes) return;
    const float* xr = &xs[ln * FDIM];
    const float* tr = &ts[ln * FDIM];
    float acc_i = 0.f, acc_c = 0.f, acc_o = 0.f;
#pragma unroll
    for (int k = 0; k < 32; ++k) {
        float xv = xr[k], tv = tr[k];
        int o0 = k * 32 + j;
        acc_i += xv * Ws[o0]        + tv * Ws[1024 + o0];
        acc_c += xv * Ws[2048 + o0] + tv * Ws[3072 + o0];
        acc_o += xv * Ws[4096 + o0] + tv * Ws[5120 + o0];
    }
    float bi = bx[0 * 32 + j] + bh[0 * 32 + j] + bg[0 * 32 + j];
    float bc = bx[2 * 32 + j] + bh[2 * 32 + j] + bg[2 * 32 + j];
    float bo = bx[3 * 32 + j] + bh[3 * 32 + j] + bg[3 * 32 + j];
    float I = 1.f / (1.f + __expf(-(acc_i + bi)));
    float T = tanhf(acc_c + bc);
    float C = I * T;
    float O = 1.f / (1.f + __expf(-(acc_o + bo + wc[2 * 32 + j] * C)));
    float H = O * tanhf(C);
    float r = fmaxf(H, 0.f) * lin_w[j];
#pragma unroll
    for (int m = 16; m > 0; m >>= 1) r += __shfl_xor(r, m, 32);
    if (j == 0) out[n] = r + lin_b[0];
}

extern "C" void kernel_launch(void* const* d_in, const int* in_sizes, int n_in,
                              void* d_out, int out_size, void* d_ws, size_t ws_size,
                              hipStream_t stream) {
    const float* x     = (const float*)d_in[0];
    const int*   ei    = (const int*)d_in[1];
    const float* w     = (const float*)d_in[2];
    const float* Wx    = (const float*)d_in[3];
    const float* bx    = (const float*)d_in[4];
    const float* bh    = (const float*)d_in[6];
    const float* wc    = (const float*)d_in[7];
    const float* bg    = (const float*)d_in[8];
    const float* lin_w = (const float*)d_in[9];
    const float* lin_b = (const float*)d_in[10];
    float*       out   = (float*)d_out;

    int n_nodes = in_sizes[0] / FDIM;
    if (n_nodes > MAX_N) n_nodes = MAX_N;
    int E = in_sizes[2];
    if (E > MAX_E) E = MAX_E;

    const int nblk = (E + T1 - 1) / T1;            // 391
    const int nc = (n_nodes + 1023) >> 10;         // 98
    const int ns = (n_nodes + 511) >> 9;           // 196
    const int nb = (n_nodes + 31) >> 5;            // 3125
    const int SA = (nc + ns) * nblk;
    const int sbA = (SA + 8191) / 8192;
    const int SB = nc * NF * NCH;
    const int sbB = (SB + 8191) / 8192;

    count1_kernel<<<nblk, 256, 0, stream>>>(ei, E, n_nodes, nblk, nc, ns);
    scan1_kernel<<<sbA, 1024, 0, stream>>>(0, SA);
    scan2_kernel<<<1, 256, 0, stream>>>(0, sbA);
    scan3_kernel<<<sbA, 1024, 0, stream>>>(0, SA);
    scatter1_kernel<<<nblk, 256, 0, stream>>>(ei, w, E, n_nodes, nblk, nc, ns);
    count2_kernel<<<nc * NCH, 256, 0, stream>>>(nblk);
    scan1_kernel<<<sbB, 1024, 0, stream>>>(1, SB);
    scan2_kernel<<<1, 256, 0, stream>>>(1, sbB);
    scan3_kernel<<<sbB, 1024, 0, stream>>>(1, SB);
    scatter2_kernel<<<nc * NCH, 256, 0, stream>>>(nblk);
    degk_kernel<<<ns, 256, 0, stream>>>(x, n_nodes, nblk, nc, ns);
    gather_kernel<<<nb, 256, 0, stream>>>(n_nodes, nblk, nc);
    gates_kernel<<<(n_nodes + 7) / 8, 256, 0, stream>>>(
        x, Wx, bx, bh, wc, bg, lin_w, lin_b, out, n_nodes);
}